// Round 9
// baseline (273.444 us; speedup 1.0000x reference)
//
#include <hip/hip_runtime.h>
#include <stdint.h>

typedef __bf16 bf16x8 __attribute__((ext_vector_type(8)));
typedef _Float16 f16x8 __attribute__((ext_vector_type(8)));
typedef float f32x4 __attribute__((ext_vector_type(4)));
typedef float f32x16 __attribute__((ext_vector_type(16)));

constexpr int Mm = 2048;      // memory length
constexpr float QSCALE = 0.18033688011112042f;  // 0.125 * log2(e)

__device__ __forceinline__ float exp2_fast(float x) {
  return __builtin_amdgcn_exp2f(x);   // v_exp_f32: native 2^x
}

__device__ __forceinline__ uint16_t f2bf(float f) {
  union { float f; uint32_t u; } v; v.f = f;
  return (uint16_t)((v.u + 0x7FFFu + ((v.u >> 16) & 1u)) >> 16);
}
__device__ __forceinline__ uint32_t pack2(float a, float b) {
  return (uint32_t)f2bf(a) | ((uint32_t)f2bf(b) << 16);
}
// packed f32x2 -> f16x2 (RTZ), single VALU op
__device__ __forceinline__ uint32_t pkrtz(float a, float b) {
  auto h2 = __builtin_amdgcn_cvt_pkrtz(a, b);
  return __builtin_bit_cast(uint32_t, h2);
}
__device__ __forceinline__ uint16_t f2h(float f) {
  _Float16 h = (_Float16)f;
  return __builtin_bit_cast(uint16_t, h);
}

// async 16B global->LDS (dest = wave-uniform base + lane*16)
__device__ __forceinline__ void async16(const void* g, void* l) {
  __builtin_amdgcn_global_load_lds(
      (__attribute__((address_space(1))) uint32_t*)g,
      (__attribute__((address_space(3))) uint32_t*)l, 16, 0, 0);
}

// 16B fragment from a [rows][64] tile (m97 layout, no pad)
__device__ __forceinline__ bf16x8 frag64(const uint16_t* base, int row, int chunk) {
  return *(const bf16x8*)(base + row * 64 + chunk * 8);
}
__device__ __forceinline__ f16x8 frag64h(const uint16_t* base, int row, int chunk) {
  return *(const f16x8*)(base + row * 64 + chunk * 8);
}

// ---------------------------------------------------------------------------
// prep: x->bf16, weight transposes, mem_k scatter (bf16),
//       mem_v TRANSPOSED scatter (fp16) -> VhT[bh][dh][key]
// R7: mem_v write phase re-mapped (d = chunk>>3, mg = chunk&7) so 8
// consecutive lanes write one 128B-contiguous run per dh row.
// ---------------------------------------------------------------------------
__global__ __launch_bounds__(256) void prep_kernel(
    const float* __restrict__ x, const float* __restrict__ mem_k,
    const float* __restrict__ mem_v, const float* __restrict__ Wq,
    const float* __restrict__ Wkv, const float* __restrict__ Wo,
    uint16_t* __restrict__ Xb, uint16_t* __restrict__ WallT,
    uint16_t* __restrict__ WoT, uint16_t* __restrict__ Kh,
    uint16_t* __restrict__ VhT) {
  __shared__ float tile[64][65];
  __shared__ uint16_t vtile[64 * 66];
  const int tid = threadIdx.x;
  int blk = blockIdx.x;

  if (blk < 1024) {  // x -> Xb
    const float4* x4 = (const float4*)x;
    for (int it = 0; it < 4; ++it) {
      int idx4 = blk * 1024 + it * 256 + tid;
      float4 v = x4[idx4];
      uint2 w; w.x = pack2(v.x, v.y); w.y = pack2(v.z, v.w);
      ((uint2*)Xb)[idx4] = w;
    }
    return;
  }
  blk -= 1024;
  if (blk < 1024) {  // weight transposes
    const float* src; uint16_t* dst; int ld, colbase, n0, k0;
    if (blk < 768) {
      int nt = blk >> 4, kt = blk & 15;
      n0 = nt * 64; k0 = kt * 64;
      if (n0 < 1024) { src = Wq; ld = 1024; colbase = n0; }
      else           { src = Wkv; ld = 2048; colbase = n0 - 1024; }
      dst = WallT;
    } else {
      int b2 = blk - 768;
      int nt = b2 >> 4, kt = b2 & 15;
      n0 = nt * 64; k0 = kt * 64;
      src = Wo; ld = 1024; colbase = n0; dst = WoT;
    }
    int r = tid >> 4, c = (tid & 15) * 4;
    for (int it = 0; it < 4; ++it) {
      int rr = r + it * 16;  // k-local
      float4 v = *(const float4*)(src + (size_t)(k0 + rr) * ld + colbase + c);
      tile[rr][c] = v.x; tile[rr][c + 1] = v.y;
      tile[rr][c + 2] = v.z; tile[rr][c + 3] = v.w;
    }
    __syncthreads();
    for (int it = 0; it < 4; ++it) {
      int rn = r + it * 16;  // n-local
      uint2 w;
      w.x = pack2(tile[c][rn], tile[c + 1][rn]);
      w.y = pack2(tile[c + 2][rn], tile[c + 3][rn]);
      *(uint2*)(dst + (size_t)(n0 + rn) * 1024 + k0 + c) = w;
    }
    return;
  }
  blk -= 1024;
  if (blk < 1024) {  // mem_k scatter -> Kh[bh][key][dh] (bf16)
    const float4* s4 = (const float4*)mem_k;
    for (int it = 0; it < 4; ++it) {
      int idx4 = blk * 1024 + it * 256 + tid;
      int e = idx4 * 4;
      int b = e >> 21;
      int rem = e & ((1 << 21) - 1);
      int m = rem >> 10;
      int cc = rem & 1023;
      int h = cc >> 6, dh = cc & 63;
      float4 v = s4[idx4];
      uint2 w; w.x = pack2(v.x, v.y); w.y = pack2(v.z, v.w);
      *(uint2*)(Kh + (((size_t)(b * 16 + h) * 4096) + m) * 64 + dh) = w;
    }
    return;
  }
  blk -= 1024;  // mem_v transpose (fp16): block = (b, h, m-tile of 64)
  {
    const int b = blk >> 9, h = (blk >> 5) & 15, m0 = (blk & 31) * 64;
    const float4* s4 = (const float4*)mem_v;
    for (int it = 0; it < 4; ++it) {
      int idx = it * 256 + tid;
      int r = idx >> 4, d4 = (idx & 15) * 4;
      float4 v = s4[(size_t)(b * 2048 + m0 + r) * 256 + h * 16 + (d4 >> 2)];
      *(uint32_t*)&vtile[r * 66 + d4]     = pkrtz(v.x, v.y);
      *(uint32_t*)&vtile[r * 66 + d4 + 2] = pkrtz(v.z, v.w);
    }
    __syncthreads();
    // write: chunk = it2*256 + tid -> d = chunk>>3, mg = chunk&7.
    // 8 consecutive lanes share d and cover mg 0..7 -> 128B contiguous runs.
    for (int it2 = 0; it2 < 2; ++it2) {
      int chunk = it2 * 256 + tid;
      int d = chunk >> 3, mg = chunk & 7;
      uint32_t w[4];
      for (int p = 0; p < 4; ++p) {
        uint32_t lo = vtile[(mg * 8 + 2 * p) * 66 + d];
        uint32_t hi = vtile[(mg * 8 + 2 * p + 1) * 66 + d];
        w[p] = lo | (hi << 16);
      }
      *(uint4*)&VhT[((size_t)((b * 16 + h) * 64) + d) * 4096 + m0 + mg * 8] =
          *(uint4*)w;
    }
  }
}

// ---------------------------------------------------------------------------
// GEMM: C[4096 x N] = A[4096 x 1024](bf16) @ Bt[N x 1024]^T(bf16)
// MODE 0: BM=128, N=3072 -> Qh bf16 (x QSCALE) / Kh bf16 (+b_kv) / VhT fp16
// MODE 1: BM=64,  N=1024 -> Out fp32 + b_o   (BM=64 -> 512 blocks = 2/CU)
// ---------------------------------------------------------------------------
template <int MODE>
__global__ __launch_bounds__(256) void gemm_kernel(
    const uint16_t* __restrict__ A, const uint16_t* __restrict__ Bt,
    const float* __restrict__ bias, uint16_t* __restrict__ Qh,
    uint16_t* __restrict__ Kh, uint16_t* __restrict__ VhT,
    float* __restrict__ Out) {
  constexpr int K = 1024;
  constexpr int SS = 136;              // C-tile staging stride (16B-aligned rows)
  constexpr int BM = (MODE == 0) ? 128 : 64;
  constexpr int MT = BM / 32;          // m-frags per wave
  constexpr int CPT = (BM + 128) * 8 / 256;   // staging chunks per thread
  const int m0 = blockIdx.x * BM, n0 = blockIdx.y * 128;
  const int tid = threadIdx.x;
  const int wave = tid >> 6, lane = tid & 63;
  const int lhi = lane >> 4, llo = lane & 15;
  const int wm = (wave >> 1) * (BM / 2), wn = (wave & 1) * 64;

  __shared__ uint16_t sh[MODE == 0 ? 128 * SS : (64 + 128) * 64];
  uint16_t* As = sh;
  uint16_t* Bs = sh + BM * 64;

  f32x4 acc[MT][4] = {};

  for (int kt = 0; kt < K / 64; ++kt) {
    __syncthreads();
    for (int c = 0; c < CPT; ++c) {
      int cl = c * 256 + tid;            // 16B chunk id (A then B, 64-aligned split)
      if (cl < BM * 8) {
        int row = cl >> 3, ch = cl & 7;
        async16(A + (size_t)(m0 + row) * K + kt * 64 + ch * 8, As + cl * 8);
      } else {
        int bl = cl - BM * 8;
        int row = bl >> 3, ch = bl & 7;
        async16(Bt + (size_t)(n0 + row) * K + kt * 64 + ch * 8, Bs + bl * 8);
      }
    }
    __syncthreads();
    for (int ks = 0; ks < 2; ++ks) {
      bf16x8 af[MT], bfr[4];
      for (int mt = 0; mt < MT; ++mt) af[mt] = frag64(As, wm + mt * 16 + llo, ks * 4 + lhi);
      for (int nt = 0; nt < 4; ++nt) bfr[nt] = frag64(Bs, wn + nt * 16 + llo, ks * 4 + lhi);
      for (int mt = 0; mt < MT; ++mt)
        for (int nt = 0; nt < 4; ++nt)
          acc[mt][nt] = __builtin_amdgcn_mfma_f32_16x16x32_bf16(af[mt], bfr[nt], acc[mt][nt], 0, 0, 0);
    }
  }

  if (MODE == 0) {
    const int region = n0 >> 10;   // 0=Q 1=K 2=V
    __syncthreads();
    for (int nt = 0; nt < 4; ++nt) {
      int cloc = wn + nt * 16 + llo;
      int col = n0 + cloc;
      float badd = (region == 0) ? 0.f : bias[col - 1024];
      for (int mt = 0; mt < 4; ++mt) {
        int rloc = wm + mt * 16 + lhi * 4;
        for (int reg = 0; reg < 4; ++reg) {
          float v = acc[mt][nt][reg];
          v = (region == 0) ? v * QSCALE : v + badd;
          if (region == 2) sh[cloc * SS + rloc + reg] = f2h(v);    // fp16, transposed
          else             sh[(rloc + reg) * SS + cloc] = f2bf(v);
        }
      }
    }
    __syncthreads();
    if (region == 2) {
      const int rl = (tid & 15) * 8;
      for (int it = 0; it < 8; ++it) {
        int cloc = (tid >> 4) + it * 16;
        int col = n0 + cloc;
        int cc = col - 2048, h = cc >> 6, dh = cc & 63;
        int r = m0 + rl;
        int b = r >> 11, n = r & 2047;
        uint4 w = *(const uint4*)&sh[cloc * SS + rl];
        *(uint4*)&VhT[((size_t)((b * 16 + h) * 64) + dh) * 4096 + 2048 + n] = w;
      }
    } else {
      const int cl16 = (tid & 15) * 8;
      const int col = n0 + cl16;
      for (int it = 0; it < 8; ++it) {
        int rloc = (tid >> 4) + it * 16;
        int r = m0 + rloc;
        int b = r >> 11, n = r & 2047;
        uint4 w = *(const uint4*)&sh[rloc * SS + cl16];
        if (region == 0) {
          int h = col >> 6, dh = col & 63;
          *(uint4*)&Qh[(((size_t)(b * 16 + h) * 2048) + n) * 64 + dh] = w;
        } else {
          int cc = col - 1024, h = cc >> 6, dh = cc & 63;
          *(uint4*)&Kh[(((size_t)(b * 16 + h) * 4096) + 2048 + n) * 64 + dh] = w;
        }
      }
    }
  } else {
    for (int nt = 0; nt < 4; ++nt) {
      int col = n0 + wn + nt * 16 + llo;
      float bo = bias[col];
      for (int mt = 0; mt < MT; ++mt) {
        int rbase = m0 + wm + mt * 16 + lhi * 4;
        for (int reg = 0; reg < 4; ++reg)
          Out[(size_t)(rbase + reg) * 1024 + col] = acc[mt][nt][reg] + bo;
      }
    }
  }
}

// ---------------------------------------------------------------------------
// Flash attention, S^T formulation, 32x32x16 MFMA, P in-register.
// Block = (bh, 128 q rows), 4 waves = 2 q-groups x 2 KEY-PARITIES.
//
// R9: PV DEFERRED BY ONE ITERATION. At iter u: QK(u) -> [PV(u-1), pure-reg
// MFMAs, issued BEFORE the exp/pack VALU phase -> matrix pipe drains under
// the 825-cyc/wave VALU block] -> exp/pack(u) -> vfr[8] <- Vt[cur] (regs,
// so PV(u) can run next iter after the buffer rotates). Breaks the serial
// QK->VALU->PV chain that kept VALU/MFMA/LDS pipes serialized (R8: pipe-sum
// ~= wall). exp+pack+l fused per octet (no e[32] transient). Register
// budget ~240 < 256 cap (2 waves/SIMD, LDS-limited occupancy).
// ---------------------------------------------------------------------------
__global__ __launch_bounds__(256, 2) void attn_kernel(
    const uint16_t* __restrict__ Qh, const uint16_t* __restrict__ Kh,
    const uint16_t* __restrict__ VhT, uint16_t* __restrict__ AO) {
  const int bh = blockIdx.x;
  const int qt = (blockIdx.y < 8) ? (15 - (int)blockIdx.y)
                                  : ((int)blockIdx.y - 8);
  const int tid = threadIdx.x;
  const int wave = tid >> 6, lane = tid & 63;
  const int lo5 = lane & 31, hi = lane >> 5;
  const int qg = wave & 1, kp = wave >> 1;
  const int i0 = qt * 128;
  const int swz5 = lo5 & 7;

  __shared__ uint16_t Ks[2][2][64 * 64];    // [buf][par][key][dh] bf16, swizzled
  __shared__ uint16_t Vt[2][2][64 * 64];    // [buf][par][dh][key] fp16, swizzled

  // Q fragments: two 32-q sub-groups; B-operand lane holds Q[q=lo5][k-slice]
  bf16x8 qf0[4], qf1[4];
  {
    const uint16_t* Qw0 = Qh + ((size_t)bh * 2048 + i0 + qg * 64 + lo5) * 64;
    const uint16_t* Qw1 = Qw0 + 32 * 64;
#pragma unroll
    for (int k = 0; k < 4; ++k) {
      qf0[k] = *(const bf16x8*)(Qw0 + k * 16 + hi * 8);
      qf1[k] = *(const bf16x8*)(Qw1 + k * 16 + hi * 8);
    }
  }

  const uint16_t* Kbh = Kh + (size_t)bh * 4096 * 64;
  const uint16_t* Vbh = VhT + (size_t)bh * 64 * 4096;

  f32x16 o00 = {}, o01 = {}, o10 = {}, o11 = {};  // [subgroup][dh-half]
  float l0p = 0.f, l1p = 0.f;                     // per-lane l partials

  const int npairs = 17 + qt;               // nkt = 34+2qt, tiles per parity

  // staging: wave -> (array, parity): w0:K/p0 w1:K/p1 w2:V/p0 w3:V/p1
  auto stage = [&](int buf, int u_) {
    const int arr = wave >> 1;
    const int par = wave & 1;
    const int kk0 = u_ * 128 + par * 64;
    uint16_t* dstb = arr == 0 ? &Ks[buf][par][0] : &Vt[buf][par][0];
#pragma unroll
    for (int c = 0; c < 8; ++c) {
      int row = c * 8 + (lane >> 3);
      int chs = (lane & 7) ^ (row & 7);     // pre-swizzled source chunk (T2)
      const uint16_t* src = arr == 0
          ? Kbh + (size_t)(kk0 + row) * 64 + chs * 8
          : Vbh + (size_t)row * 4096 + kk0 + chs * 8;
      async16(src, dstb + c * 512);
    }
  };

  stage(0, 0);

  const int iw0 = i0 + qg * 64;             // subgroup 0 q base
  const int iw1 = iw0 + 32;                 // subgroup 1 q base

  // cross-iteration state: P fragments (pw) and V fragments (vfr) of the
  // PREVIOUS pair-iter. All constant-indexed (rule #20).
  uint32_t pw0[2][2][4], pw1[2][2][4];      // [mblk][kk2][word]
  f16x8 vfr[8];                             // [2*kk + dh-half]

  for (int u = 0; u < npairs; ++u) {
    const int cur = u & 1;
    __syncthreads();                         // drains+publishes buf[cur]
    if (u + 1 < npairs) stage(cur ^ 1, u + 1);

    const int k0t = (2 * u + kp) * 64;
    const uint16_t* Kt = &Ks[cur][kp][0];
    const uint16_t* Vtt = &Vt[cur][kp][0];

#pragma unroll
    for (int mblk = 0; mblk < 2; ++mblk) {
      // S^T = K·Q^T for both sub-groups, K-fragments shared
      f32x16 s0v = {}, s1v = {};
      __builtin_amdgcn_s_setprio(1);
#pragma unroll
      for (int kstep = 0; kstep < 4; ++kstep) {
        bf16x8 kf = frag64(Kt, mblk * 32 + lo5, (2 * kstep + hi) ^ swz5);
        s0v = __builtin_amdgcn_mfma_f32_32x32x16_bf16(kf, qf0[kstep], s0v, 0, 0, 0);
        s1v = __builtin_amdgcn_mfma_f32_32x32x16_bf16(kf, qf1[kstep], s1v, 0, 0, 0);
      }
      __builtin_amdgcn_s_setprio(0);

      if (mblk == 0) {
        // deferred PV for the PREVIOUS pair-iter: pure-register MFMAs,
        // independent of this iter's s/exp chain -> overlaps the VALU below
        if (u > 0) {
          __builtin_amdgcn_s_setprio(1);
#pragma unroll
          for (int pm = 0; pm < 2; ++pm)
#pragma unroll
            for (int kk2 = 0; kk2 < 2; ++kk2) {
              const int kk = pm * 2 + kk2;
              uint4 fwa; fwa.x = pw0[pm][kk2][0]; fwa.y = pw0[pm][kk2][1];
              fwa.z = pw0[pm][kk2][2]; fwa.w = pw0[pm][kk2][3];
              f16x8 pa0 = __builtin_bit_cast(f16x8, fwa);
              uint4 fwb; fwb.x = pw1[pm][kk2][0]; fwb.y = pw1[pm][kk2][1];
              fwb.z = pw1[pm][kk2][2]; fwb.w = pw1[pm][kk2][3];
              f16x8 pa1 = __builtin_bit_cast(f16x8, fwb);
              o00 = __builtin_amdgcn_mfma_f32_32x32x16_f16(pa0, vfr[2 * kk + 0], o00, 0, 0, 0);
              o01 = __builtin_amdgcn_mfma_f32_32x32x16_f16(pa0, vfr[2 * kk + 1], o01, 0, 0, 0);
              o10 = __builtin_amdgcn_mfma_f32_32x32x16_f16(pa1, vfr[2 * kk + 0], o10, 0, 0, 0);
              o11 = __builtin_amdgcn_mfma_f32_32x32x16_f16(pa1, vfr[2 * kk + 1], o11, 0, 0, 0);
            }
          __builtin_amdgcn_s_setprio(0);
        }
        // refill V fragments from CURRENT tile (regs survive the next
        // barrier; buf[cur] itself is overwritten by stage(u+2))
#pragma unroll
        for (int kk = 0; kk < 4; ++kk) {
          vfr[2 * kk + 0] = frag64h(Vtt, lo5,      (2 * kk + hi) ^ swz5);
          vfr[2 * kk + 1] = frag64h(Vtt, 32 + lo5, (2 * kk + hi) ^ swz5);
        }
      }

      // causal mask: key j valid iff j <= Mm + q (wave-uniform branch)
      if (k0t + mblk * 32 + 31 > Mm + iw0) {
        const int lim = Mm + iw0 + lo5 - k0t - mblk * 32;
#pragma unroll
        for (int r = 0; r < 16; ++r) {
          int kl = (r & 3) + 8 * (r >> 2) + 4 * hi;
          if (kl > lim) s0v[r] = -INFINITY;
        }
      }
      if (k0t + mblk * 32 + 31 > Mm + iw1) {
        const int lim = Mm + iw1 + lo5 - k0t - mblk * 32;
#pragma unroll
        for (int r = 0; r < 16; ++r) {
          int kl = (r & 3) + 8 * (r >> 2) + 4 * hi;
          if (kl > lim) s1v[r] = -INFINITY;
        }
      }

      // fused exp2 -> l accumulate -> fp16 pack (per octet; no e[] array)
      uint32_t c0[8], c1[8];
#pragma unroll
      for (int w = 0; w < 8; ++w) {
        float a0 = exp2_fast(s0v[2 * w]), a1 = exp2_fast(s0v[2 * w + 1]);
        c0[w] = pkrtz(a0, a1);
        l0p += a0 + a1;
        float b0 = exp2_fast(s1v[2 * w]), b1 = exp2_fast(s1v[2 * w + 1]);
        c1[w] = pkrtz(b0, b1);
        l1p += b0 + b1;
      }
      // permlane32_swap -> PV A-fragment words (consumed NEXT iter)
#pragma unroll
      for (int kk2 = 0; kk2 < 2; ++kk2) {
        uint32_t a0 = c0[4 * kk2 + 0], a2 = c0[4 * kk2 + 2];
        uint32_t a1 = c0[4 * kk2 + 1], a3 = c0[4 * kk2 + 3];
        asm volatile("v_permlane32_swap_b32 %0, %1" : "+v"(a0), "+v"(a2));
        asm volatile("v_permlane32_swap_b32 %0, %1" : "+v"(a1), "+v"(a3));
        pw0[mblk][kk2][0] = a0; pw0[mblk][kk2][1] = a1;
        pw0[mblk][kk2][2] = a2; pw0[mblk][kk2][3] = a3;
        uint32_t b0 = c1[4 * kk2 + 0], b2 = c1[4 * kk2 + 2];
        uint32_t b1 = c1[4 * kk2 + 1], b3 = c1[4 * kk2 + 3];
        asm volatile("v_permlane32_swap_b32 %0, %1" : "+v"(b0), "+v"(b2));
        asm volatile("v_permlane32_swap_b32 %0, %1" : "+v"(b1), "+v"(b3));
        pw1[mblk][kk2][0] = b0; pw1[mblk][kk2][1] = b1;
        pw1[mblk][kk2][2] = b2; pw1[mblk][kk2][3] = b3;
      }
    }
  }

  // final deferred PV for the last pair-iter
  __builtin_amdgcn_s_setprio(1);
#pragma unroll
  for (int pm = 0; pm < 2; ++pm)
#pragma unroll
    for (int kk2 = 0; kk2 < 2; ++kk2) {
      const int kk = pm * 2 + kk2;
      uint4 fwa; fwa.x = pw0[pm][kk2][0]; fwa.y = pw0[pm][kk2][1];
      fwa.z = pw0[pm][kk2][2]; fwa.w = pw0[pm][kk2][3];
      f16x8 pa0 = __builtin_bit_cast(f16x8, fwa);
      uint4 fwb; fwb.x = pw1[pm][kk2][0]; fwb.y = pw1[pm][kk2][1];
      fwb.z = pw1[pm][kk2][2]; fwb.w = pw1[pm][kk2][3];
      f16x8 pa1 = __builtin_bit_cast(f16x8, fwb);
      o00 = __builtin_amdgcn_mfma_f32_32x32x16_f16(pa0, vfr[2 * kk + 0], o00, 0, 0, 0);
      o01 = __builtin_amdgcn_mfma_f32_32x32x16_f16(pa0, vfr[2 * kk + 1], o01, 0, 0, 0);
      o10 = __builtin_amdgcn_mfma_f32_32x32x16_f16(pa1, vfr[2 * kk + 0], o10, 0, 0, 0);
      o11 = __builtin_amdgcn_mfma_f32_32x32x16_f16(pa1, vfr[2 * kk + 1], o11, 0, 0, 0);
    }
  __builtin_amdgcn_s_setprio(0);

  // cross-hi combine of l partials: one permlane32_swap + add each
  float l0full, l1full;
  {
    float a0 = l0p, b0 = l0p;
    asm volatile("v_permlane32_swap_b32 %0, %1" : "+v"(a0), "+v"(b0));
    l0full = a0 + b0;                       // all lanes: full l for q=qg*64+lo5 (this kp)
    float a1 = l1p, b1 = l1p;
    asm volatile("v_permlane32_swap_b32 %0, %1" : "+v"(a1), "+v"(b1));
    l1full = a1 + b1;
  }

  // epilogue: combine kp partials via LDS, normalize, stage bf16, write out
  const int b = bh >> 4, h = bh & 15;
  float* F = (float*)&Ks[0][0][0];          // 32 KB: [128 q][64 dh] f32
  float* L = (float*)&Vt[1][0][0];          // 1 KB:  [kp][128 q] f32
  uint16_t* Es = &Vt[0][0][0];              // 16 KB: [128 q][64 dh] bf16

  __syncthreads();
  if (hi == 0) {
    L[kp * 128 + qg * 64 + lo5]      = l0full;
    L[kp * 128 + qg * 64 + 32 + lo5] = l1full;
  }
  if (kp == 1) {
#pragma unroll
    for (int r = 0; r < 16; ++r) {
      int q0 = qg * 64 + (r & 3) + 8 * (r >> 2) + 4 * hi;
      int q1 = q0 + 32;
      F[q0 * 64 + lo5]      = o00[r];
      F[q0 * 64 + 32 + lo5] = o01[r];
      F[q1 * 64 + lo5]      = o10[r];
      F[q1 * 64 + 32 + lo5] = o11[r];
    }
  }
  __syncthreads();
  if (kp == 0) {
#pragma unroll
    for (int r = 0; r < 16; ++r) {
      int q0 = qg * 64 + (r & 3) + 8 * (r >> 2) + 4 * hi;
      int q1 = q0 + 32;
      float inv0 = 1.0f / (L[q0] + L[128 + q0]);   // broadcast reads
      float inv1 = 1.0f / (L[q1] + L[128 + q1]);
      Es[q0 * 64 + lo5]      = f2bf((o00[r] + F[q0 * 64 + lo5]) * inv0);
      Es[q0 * 64 + 32 + lo5] = f2bf((o01[r] + F[q0 * 64 + 32 + lo5]) * inv0);
      Es[q1 * 64 + lo5]      = f2bf((o10[r] + F[q1 * 64 + lo5]) * inv1);
      Es[q1 * 64 + 32 + lo5] = f2bf((o11[r] + F[q1 * 64 + 32 + lo5]) * inv1);
    }
  }
  __syncthreads();
  {
    int row = tid >> 1, c32 = (tid & 1) * 32;   // 256 threads -> 128 rows
    size_t base = ((size_t)(b * 2048) + i0 + row) * 1024 + h * 64 + c32;
    *(uint4*)&AO[base]      = *(const uint4*)&Es[row * 64 + c32];
    *(uint4*)&AO[base + 8]  = *(const uint4*)&Es[row * 64 + c32 + 8];
    *(uint4*)&AO[base + 16] = *(const uint4*)&Es[row * 64 + c32 + 16];
    *(uint4*)&AO[base + 24] = *(const uint4*)&Es[row * 64 + c32 + 24];
  }
}

// ---------------------------------------------------------------------------
extern "C" void kernel_launch(void* const* d_in, const int* in_sizes, int n_in,
                              void* d_out, int out_size, void* d_ws,
                              size_t ws_size, hipStream_t stream) {
  const float* x     = (const float*)d_in[0];
  const float* mem_k = (const float*)d_in[1];
  const float* mem_v = (const float*)d_in[2];
  const float* Wq    = (const float*)d_in[3];
  const float* Wkv   = (const float*)d_in[4];
  const float* b_kv  = (const float*)d_in[5];
  const float* Wo    = (const float*)d_in[6];
  const float* b_o   = (const float*)d_in[7];
  float* out = (float*)d_out;

  char* ws = (char*)d_ws;
  uint16_t* Xb    = (uint16_t*)(ws);                         // 8 MB  [4096][1024]
  uint16_t* WallT = (uint16_t*)(ws + (8ull << 20));          // 6 MB  [3072][1024]
  uint16_t* WoT   = (uint16_t*)(ws + (14ull << 20));         // 2 MB  [1024][1024]
  uint16_t* Qh    = (uint16_t*)(ws + (16ull << 20));         // 8 MB  [bh][2048][64]
  uint16_t* Kh    = (uint16_t*)(ws + (24ull << 20));         // 16 MB [bh][4096][64] bf16
  uint16_t* VhT   = (uint16_t*)(ws + (40ull << 20));         // 16 MB [bh][64][4096] fp16
  uint16_t* AO    = (uint16_t*)(ws + (56ull << 20));         // 8 MB  [4096][1024]

  prep_kernel<<<4096, 256, 0, stream>>>(x, mem_k, mem_v, Wq, Wkv, Wo,
                                        Xb, WallT, WoT, Kh, VhT);
  gemm_kernel<0><<<dim3(32, 24), 256, 0, stream>>>(Xb, WallT, b_kv,
                                                   Qh, Kh, VhT, nullptr);
  attn_kernel<<<dim3(32, 16), 256, 0, stream>>>(Qh, Kh, VhT, AO);
  gemm_kernel<1><<<dim3(64, 8), 256, 0, stream>>>(AO, WoT, b_o,
                                                  nullptr, nullptr, nullptr, out);
}

// Round 10
// 232.962 us; speedup vs baseline: 1.1738x; 1.1738x over previous
//
#include <hip/hip_runtime.h>
#include <stdint.h>

typedef __bf16 bf16x8 __attribute__((ext_vector_type(8)));
typedef _Float16 f16x8 __attribute__((ext_vector_type(8)));
typedef float f32x4 __attribute__((ext_vector_type(4)));
typedef float f32x16 __attribute__((ext_vector_type(16)));

constexpr int Mm = 2048;      // memory length
constexpr float QSCALE = 0.18033688011112042f;  // 0.125 * log2(e)

__device__ __forceinline__ float exp2_fast(float x) {
  return __builtin_amdgcn_exp2f(x);   // v_exp_f32: native 2^x
}

__device__ __forceinline__ uint16_t f2bf(float f) {
  union { float f; uint32_t u; } v; v.f = f;
  return (uint16_t)((v.u + 0x7FFFu + ((v.u >> 16) & 1u)) >> 16);
}
__device__ __forceinline__ uint32_t pack2(float a, float b) {
  return (uint32_t)f2bf(a) | ((uint32_t)f2bf(b) << 16);
}
// packed f32x2 -> f16x2 (RTZ), single VALU op
__device__ __forceinline__ uint32_t pkrtz(float a, float b) {
  auto h2 = __builtin_amdgcn_cvt_pkrtz(a, b);
  return __builtin_bit_cast(uint32_t, h2);
}
__device__ __forceinline__ uint16_t f2h(float f) {
  _Float16 h = (_Float16)f;
  return __builtin_bit_cast(uint16_t, h);
}

// async 16B global->LDS (dest = wave-uniform base + lane*16)
__device__ __forceinline__ void async16(const void* g, void* l) {
  __builtin_amdgcn_global_load_lds(
      (__attribute__((address_space(1))) uint32_t*)g,
      (__attribute__((address_space(3))) uint32_t*)l, 16, 0, 0);
}

// 16B fragment from a [rows][64] tile (m97 layout, no pad)
__device__ __forceinline__ bf16x8 frag64(const uint16_t* base, int row, int chunk) {
  return *(const bf16x8*)(base + row * 64 + chunk * 8);
}
__device__ __forceinline__ f16x8 frag64h(const uint16_t* base, int row, int chunk) {
  return *(const f16x8*)(base + row * 64 + chunk * 8);
}

// ---------------------------------------------------------------------------
// prep: x->bf16, weight transposes, mem_k scatter (bf16),
//       mem_v TRANSPOSED scatter (fp16) -> VhT[bh][dh][key]
// R7: mem_v write phase re-mapped (d = chunk>>3, mg = chunk&7) so 8
// consecutive lanes write one 128B-contiguous run per dh row.
// ---------------------------------------------------------------------------
__global__ __launch_bounds__(256) void prep_kernel(
    const float* __restrict__ x, const float* __restrict__ mem_k,
    const float* __restrict__ mem_v, const float* __restrict__ Wq,
    const float* __restrict__ Wkv, const float* __restrict__ Wo,
    uint16_t* __restrict__ Xb, uint16_t* __restrict__ WallT,
    uint16_t* __restrict__ WoT, uint16_t* __restrict__ Kh,
    uint16_t* __restrict__ VhT) {
  __shared__ float tile[64][65];
  __shared__ uint16_t vtile[64 * 66];
  const int tid = threadIdx.x;
  int blk = blockIdx.x;

  if (blk < 1024) {  // x -> Xb
    const float4* x4 = (const float4*)x;
    for (int it = 0; it < 4; ++it) {
      int idx4 = blk * 1024 + it * 256 + tid;
      float4 v = x4[idx4];
      uint2 w; w.x = pack2(v.x, v.y); w.y = pack2(v.z, v.w);
      ((uint2*)Xb)[idx4] = w;
    }
    return;
  }
  blk -= 1024;
  if (blk < 1024) {  // weight transposes
    const float* src; uint16_t* dst; int ld, colbase, n0, k0;
    if (blk < 768) {
      int nt = blk >> 4, kt = blk & 15;
      n0 = nt * 64; k0 = kt * 64;
      if (n0 < 1024) { src = Wq; ld = 1024; colbase = n0; }
      else           { src = Wkv; ld = 2048; colbase = n0 - 1024; }
      dst = WallT;
    } else {
      int b2 = blk - 768;
      int nt = b2 >> 4, kt = b2 & 15;
      n0 = nt * 64; k0 = kt * 64;
      src = Wo; ld = 1024; colbase = n0; dst = WoT;
    }
    int r = tid >> 4, c = (tid & 15) * 4;
    for (int it = 0; it < 4; ++it) {
      int rr = r + it * 16;  // k-local
      float4 v = *(const float4*)(src + (size_t)(k0 + rr) * ld + colbase + c);
      tile[rr][c] = v.x; tile[rr][c + 1] = v.y;
      tile[rr][c + 2] = v.z; tile[rr][c + 3] = v.w;
    }
    __syncthreads();
    for (int it = 0; it < 4; ++it) {
      int rn = r + it * 16;  // n-local
      uint2 w;
      w.x = pack2(tile[c][rn], tile[c + 1][rn]);
      w.y = pack2(tile[c + 2][rn], tile[c + 3][rn]);
      *(uint2*)(dst + (size_t)(n0 + rn) * 1024 + k0 + c) = w;
    }
    return;
  }
  blk -= 1024;
  if (blk < 1024) {  // mem_k scatter -> Kh[bh][key][dh] (bf16)
    const float4* s4 = (const float4*)mem_k;
    for (int it = 0; it < 4; ++it) {
      int idx4 = blk * 1024 + it * 256 + tid;
      int e = idx4 * 4;
      int b = e >> 21;
      int rem = e & ((1 << 21) - 1);
      int m = rem >> 10;
      int cc = rem & 1023;
      int h = cc >> 6, dh = cc & 63;
      float4 v = s4[idx4];
      uint2 w; w.x = pack2(v.x, v.y); w.y = pack2(v.z, v.w);
      *(uint2*)(Kh + (((size_t)(b * 16 + h) * 4096) + m) * 64 + dh) = w;
    }
    return;
  }
  blk -= 1024;  // mem_v transpose (fp16): block = (b, h, m-tile of 64)
  {
    const int b = blk >> 9, h = (blk >> 5) & 15, m0 = (blk & 31) * 64;
    const float4* s4 = (const float4*)mem_v;
    for (int it = 0; it < 4; ++it) {
      int idx = it * 256 + tid;
      int r = idx >> 4, d4 = (idx & 15) * 4;
      float4 v = s4[(size_t)(b * 2048 + m0 + r) * 256 + h * 16 + (d4 >> 2)];
      *(uint32_t*)&vtile[r * 66 + d4]     = pkrtz(v.x, v.y);
      *(uint32_t*)&vtile[r * 66 + d4 + 2] = pkrtz(v.z, v.w);
    }
    __syncthreads();
    // write: chunk = it2*256 + tid -> d = chunk>>3, mg = chunk&7.
    // 8 consecutive lanes share d and cover mg 0..7 -> 128B contiguous runs.
    for (int it2 = 0; it2 < 2; ++it2) {
      int chunk = it2 * 256 + tid;
      int d = chunk >> 3, mg = chunk & 7;
      uint32_t w[4];
      for (int p = 0; p < 4; ++p) {
        uint32_t lo = vtile[(mg * 8 + 2 * p) * 66 + d];
        uint32_t hi = vtile[(mg * 8 + 2 * p + 1) * 66 + d];
        w[p] = lo | (hi << 16);
      }
      *(uint4*)&VhT[((size_t)((b * 16 + h) * 64) + d) * 4096 + m0 + mg * 8] =
          *(uint4*)w;
    }
  }
}

// ---------------------------------------------------------------------------
// GEMM: C[4096 x N] = A[4096 x 1024](bf16) @ Bt[N x 1024]^T(bf16)
// MODE 0: BM=128, N=3072 -> Qh bf16 (x QSCALE) / Kh bf16 (+b_kv) / VhT fp16
// MODE 1: BM=64,  N=1024 -> Out fp32 + b_o   (BM=64 -> 512 blocks = 2/CU)
// ---------------------------------------------------------------------------
template <int MODE>
__global__ __launch_bounds__(256) void gemm_kernel(
    const uint16_t* __restrict__ A, const uint16_t* __restrict__ Bt,
    const float* __restrict__ bias, uint16_t* __restrict__ Qh,
    uint16_t* __restrict__ Kh, uint16_t* __restrict__ VhT,
    float* __restrict__ Out) {
  constexpr int K = 1024;
  constexpr int SS = 136;              // C-tile staging stride (16B-aligned rows)
  constexpr int BM = (MODE == 0) ? 128 : 64;
  constexpr int MT = BM / 32;          // m-frags per wave
  constexpr int CPT = (BM + 128) * 8 / 256;   // staging chunks per thread
  const int m0 = blockIdx.x * BM, n0 = blockIdx.y * 128;
  const int tid = threadIdx.x;
  const int wave = tid >> 6, lane = tid & 63;
  const int lhi = lane >> 4, llo = lane & 15;
  const int wm = (wave >> 1) * (BM / 2), wn = (wave & 1) * 64;

  __shared__ uint16_t sh[MODE == 0 ? 128 * SS : (64 + 128) * 64];
  uint16_t* As = sh;
  uint16_t* Bs = sh + BM * 64;

  f32x4 acc[MT][4] = {};

  for (int kt = 0; kt < K / 64; ++kt) {
    __syncthreads();
    for (int c = 0; c < CPT; ++c) {
      int cl = c * 256 + tid;            // 16B chunk id (A then B, 64-aligned split)
      if (cl < BM * 8) {
        int row = cl >> 3, ch = cl & 7;
        async16(A + (size_t)(m0 + row) * K + kt * 64 + ch * 8, As + cl * 8);
      } else {
        int bl = cl - BM * 8;
        int row = bl >> 3, ch = bl & 7;
        async16(Bt + (size_t)(n0 + row) * K + kt * 64 + ch * 8, Bs + bl * 8);
      }
    }
    __syncthreads();
    for (int ks = 0; ks < 2; ++ks) {
      bf16x8 af[MT], bfr[4];
      for (int mt = 0; mt < MT; ++mt) af[mt] = frag64(As, wm + mt * 16 + llo, ks * 4 + lhi);
      for (int nt = 0; nt < 4; ++nt) bfr[nt] = frag64(Bs, wn + nt * 16 + llo, ks * 4 + lhi);
      for (int mt = 0; mt < MT; ++mt)
        for (int nt = 0; nt < 4; ++nt)
          acc[mt][nt] = __builtin_amdgcn_mfma_f32_16x16x32_bf16(af[mt], bfr[nt], acc[mt][nt], 0, 0, 0);
    }
  }

  if (MODE == 0) {
    const int region = n0 >> 10;   // 0=Q 1=K 2=V
    __syncthreads();
    for (int nt = 0; nt < 4; ++nt) {
      int cloc = wn + nt * 16 + llo;
      int col = n0 + cloc;
      float badd = (region == 0) ? 0.f : bias[col - 1024];
      for (int mt = 0; mt < 4; ++mt) {
        int rloc = wm + mt * 16 + lhi * 4;
        for (int reg = 0; reg < 4; ++reg) {
          float v = acc[mt][nt][reg];
          v = (region == 0) ? v * QSCALE : v + badd;
          if (region == 2) sh[cloc * SS + rloc + reg] = f2h(v);    // fp16, transposed
          else             sh[(rloc + reg) * SS + cloc] = f2bf(v);
        }
      }
    }
    __syncthreads();
    if (region == 2) {
      const int rl = (tid & 15) * 8;
      for (int it = 0; it < 8; ++it) {
        int cloc = (tid >> 4) + it * 16;
        int col = n0 + cloc;
        int cc = col - 2048, h = cc >> 6, dh = cc & 63;
        int r = m0 + rl;
        int b = r >> 11, n = r & 2047;
        uint4 w = *(const uint4*)&sh[cloc * SS + rl];
        *(uint4*)&VhT[((size_t)((b * 16 + h) * 64) + dh) * 4096 + 2048 + n] = w;
      }
    } else {
      const int cl16 = (tid & 15) * 8;
      const int col = n0 + cl16;
      for (int it = 0; it < 8; ++it) {
        int rloc = (tid >> 4) + it * 16;
        int r = m0 + rloc;
        int b = r >> 11, n = r & 2047;
        uint4 w = *(const uint4*)&sh[rloc * SS + cl16];
        if (region == 0) {
          int h = col >> 6, dh = col & 63;
          *(uint4*)&Qh[(((size_t)(b * 16 + h) * 2048) + n) * 64 + dh] = w;
        } else {
          int cc = col - 1024, h = cc >> 6, dh = cc & 63;
          *(uint4*)&Kh[(((size_t)(b * 16 + h) * 4096) + 2048 + n) * 64 + dh] = w;
        }
      }
    }
  } else {
    for (int nt = 0; nt < 4; ++nt) {
      int col = n0 + wn + nt * 16 + llo;
      float bo = bias[col];
      for (int mt = 0; mt < MT; ++mt) {
        int rbase = m0 + wm + mt * 16 + lhi * 4;
        for (int reg = 0; reg < 4; ++reg)
          Out[(size_t)(rbase + reg) * 1024 + col] = acc[mt][nt][reg] + bo;
      }
    }
  }
}

// ---------------------------------------------------------------------------
// Flash attention, S^T formulation, 32x32x16 MFMA, P in-register.
// Block = (bh, 128 q rows), 4 waves = 2 q-groups x 2 KEY-PARITIES.
//
// R10: INTRA-ITERATION PV deferral, no cross-barrier state. Per pair-iter:
//   QK(m0) -> exp/pack(m0) -> QK(m1) -> PV(m0) -> exp/pack(m1) -> PV(m1)
// PV(m0) (8 pure MFMA + 4 LDS V reads) is independent of the s(m1) chain:
// once issued, the matrix pipe drains UNDER the 32-exp VALU block after it.
// All s_setprio fences removed from the main loop (they are side-effecting
// intrinsics that forbid the scheduler from interleaving MFMA with VALU —
// and measured null-to-negative on barrier-locked structures, m190).
// pw live state: ONE mblk (16 regs, was 32). No state across barriers
// (the R6/R9 spill failure mode).
// ---------------------------------------------------------------------------
__global__ __launch_bounds__(256, 2) void attn_kernel(
    const uint16_t* __restrict__ Qh, const uint16_t* __restrict__ Kh,
    const uint16_t* __restrict__ VhT, uint16_t* __restrict__ AO) {
  const int bh = blockIdx.x;
  const int qt = (blockIdx.y < 8) ? (15 - (int)blockIdx.y)
                                  : ((int)blockIdx.y - 8);
  const int tid = threadIdx.x;
  const int wave = tid >> 6, lane = tid & 63;
  const int lo5 = lane & 31, hi = lane >> 5;
  const int qg = wave & 1, kp = wave >> 1;
  const int i0 = qt * 128;
  const int swz5 = lo5 & 7;

  __shared__ uint16_t Ks[2][2][64 * 64];    // [buf][par][key][dh] bf16, swizzled
  __shared__ uint16_t Vt[2][2][64 * 64];    // [buf][par][dh][key] fp16, swizzled

  // Q fragments: two 32-q sub-groups; B-operand lane holds Q[q=lo5][k-slice]
  bf16x8 qf0[4], qf1[4];
  {
    const uint16_t* Qw0 = Qh + ((size_t)bh * 2048 + i0 + qg * 64 + lo5) * 64;
    const uint16_t* Qw1 = Qw0 + 32 * 64;
#pragma unroll
    for (int k = 0; k < 4; ++k) {
      qf0[k] = *(const bf16x8*)(Qw0 + k * 16 + hi * 8);
      qf1[k] = *(const bf16x8*)(Qw1 + k * 16 + hi * 8);
    }
  }

  const uint16_t* Kbh = Kh + (size_t)bh * 4096 * 64;
  const uint16_t* Vbh = VhT + (size_t)bh * 64 * 4096;

  f32x16 o00 = {}, o01 = {}, o10 = {}, o11 = {};  // [subgroup][dh-half]
  float l0p = 0.f, l1p = 0.f;                     // per-lane l partials

  const int npairs = 17 + qt;               // nkt = 34+2qt, tiles per parity

  // staging: wave -> (array, parity): w0:K/p0 w1:K/p1 w2:V/p0 w3:V/p1
  auto stage = [&](int buf, int u_) {
    const int arr = wave >> 1;
    const int par = wave & 1;
    const int kk0 = u_ * 128 + par * 64;
    uint16_t* dstb = arr == 0 ? &Ks[buf][par][0] : &Vt[buf][par][0];
#pragma unroll
    for (int c = 0; c < 8; ++c) {
      int row = c * 8 + (lane >> 3);
      int chs = (lane & 7) ^ (row & 7);     // pre-swizzled source chunk (T2)
      const uint16_t* src = arr == 0
          ? Kbh + (size_t)(kk0 + row) * 64 + chs * 8
          : Vbh + (size_t)row * 4096 + kk0 + chs * 8;
      async16(src, dstb + c * 512);
    }
  };

  stage(0, 0);

  const int iw0 = i0 + qg * 64;             // subgroup 0 q base
  const int iw1 = iw0 + 32;                 // subgroup 1 q base

  // per-mblk helpers operating on straight-line locals (rule #20 safe)
  for (int u = 0; u < npairs; ++u) {
    const int cur = u & 1;
    __syncthreads();                         // drains+publishes buf[cur]
    if (u + 1 < npairs) stage(cur ^ 1, u + 1);

    const int k0t = (2 * u + kp) * 64;
    const uint16_t* Kt = &Ks[cur][kp][0];
    const uint16_t* Vtt = &Vt[cur][kp][0];

    uint32_t pwA0[2][4], pwA1[2][4];         // pw of mblk currently deferred
    uint32_t pwB0[2][4], pwB1[2][4];         // pw of mblk1

    // ---- phase A: QK(m0) + exp/pack(m0) ----
    {
      f32x16 s0v = {}, s1v = {};
#pragma unroll
      for (int kstep = 0; kstep < 4; ++kstep) {
        bf16x8 kf = frag64(Kt, lo5, (2 * kstep + hi) ^ swz5);
        s0v = __builtin_amdgcn_mfma_f32_32x32x16_bf16(kf, qf0[kstep], s0v, 0, 0, 0);
        s1v = __builtin_amdgcn_mfma_f32_32x32x16_bf16(kf, qf1[kstep], s1v, 0, 0, 0);
      }
      if (k0t + 31 > Mm + iw0) {
        const int lim = Mm + iw0 + lo5 - k0t;
#pragma unroll
        for (int r = 0; r < 16; ++r) {
          int kl = (r & 3) + 8 * (r >> 2) + 4 * hi;
          if (kl > lim) s0v[r] = -INFINITY;
        }
      }
      if (k0t + 31 > Mm + iw1) {
        const int lim = Mm + iw1 + lo5 - k0t;
#pragma unroll
        for (int r = 0; r < 16; ++r) {
          int kl = (r & 3) + 8 * (r >> 2) + 4 * hi;
          if (kl > lim) s1v[r] = -INFINITY;
        }
      }
      uint32_t c0[8], c1[8];
#pragma unroll
      for (int w = 0; w < 8; ++w) {
        float a0 = exp2_fast(s0v[2 * w]), a1 = exp2_fast(s0v[2 * w + 1]);
        c0[w] = pkrtz(a0, a1);
        l0p += a0 + a1;
        float b0 = exp2_fast(s1v[2 * w]), b1 = exp2_fast(s1v[2 * w + 1]);
        c1[w] = pkrtz(b0, b1);
        l1p += b0 + b1;
      }
#pragma unroll
      for (int kk2 = 0; kk2 < 2; ++kk2) {
        uint32_t a0 = c0[4 * kk2 + 0], a2 = c0[4 * kk2 + 2];
        uint32_t a1 = c0[4 * kk2 + 1], a3 = c0[4 * kk2 + 3];
        asm volatile("v_permlane32_swap_b32 %0, %1" : "+v"(a0), "+v"(a2));
        asm volatile("v_permlane32_swap_b32 %0, %1" : "+v"(a1), "+v"(a3));
        pwA0[kk2][0] = a0; pwA0[kk2][1] = a1; pwA0[kk2][2] = a2; pwA0[kk2][3] = a3;
        uint32_t b0 = c1[4 * kk2 + 0], b2 = c1[4 * kk2 + 2];
        uint32_t b1 = c1[4 * kk2 + 1], b3 = c1[4 * kk2 + 3];
        asm volatile("v_permlane32_swap_b32 %0, %1" : "+v"(b0), "+v"(b2));
        asm volatile("v_permlane32_swap_b32 %0, %1" : "+v"(b1), "+v"(b3));
        pwA1[kk2][0] = b0; pwA1[kk2][1] = b1; pwA1[kk2][2] = b2; pwA1[kk2][3] = b3;
      }
    }

    // ---- phase B: QK(m1), then PV(m0) issued BEFORE exp(m1) ----
    f32x16 s0v = {}, s1v = {};
#pragma unroll
    for (int kstep = 0; kstep < 4; ++kstep) {
      bf16x8 kf = frag64(Kt, 32 + lo5, (2 * kstep + hi) ^ swz5);
      s0v = __builtin_amdgcn_mfma_f32_32x32x16_bf16(kf, qf0[kstep], s0v, 0, 0, 0);
      s1v = __builtin_amdgcn_mfma_f32_32x32x16_bf16(kf, qf1[kstep], s1v, 0, 0, 0);
    }
    // PV(m0): kk = 0,1 — matrix pipe drains under the exp block below
#pragma unroll
    for (int kk2 = 0; kk2 < 2; ++kk2) {
      const int kk = kk2;
      uint4 fwa; fwa.x = pwA0[kk2][0]; fwa.y = pwA0[kk2][1];
      fwa.z = pwA0[kk2][2]; fwa.w = pwA0[kk2][3];
      f16x8 pa0 = __builtin_bit_cast(f16x8, fwa);
      uint4 fwb; fwb.x = pwA1[kk2][0]; fwb.y = pwA1[kk2][1];
      fwb.z = pwA1[kk2][2]; fwb.w = pwA1[kk2][3];
      f16x8 pa1 = __builtin_bit_cast(f16x8, fwb);
      f16x8 vf0 = frag64h(Vtt, lo5,      (2 * kk + hi) ^ swz5);
      f16x8 vf1 = frag64h(Vtt, 32 + lo5, (2 * kk + hi) ^ swz5);
      o00 = __builtin_amdgcn_mfma_f32_32x32x16_f16(pa0, vf0, o00, 0, 0, 0);
      o01 = __builtin_amdgcn_mfma_f32_32x32x16_f16(pa0, vf1, o01, 0, 0, 0);
      o10 = __builtin_amdgcn_mfma_f32_32x32x16_f16(pa1, vf0, o10, 0, 0, 0);
      o11 = __builtin_amdgcn_mfma_f32_32x32x16_f16(pa1, vf1, o11, 0, 0, 0);
    }
    // exp/pack(m1)
    if (k0t + 63 > Mm + iw0) {
      const int lim = Mm + iw0 + lo5 - k0t - 32;
#pragma unroll
      for (int r = 0; r < 16; ++r) {
        int kl = (r & 3) + 8 * (r >> 2) + 4 * hi;
        if (kl > lim) s0v[r] = -INFINITY;
      }
    }
    if (k0t + 63 > Mm + iw1) {
      const int lim = Mm + iw1 + lo5 - k0t - 32;
#pragma unroll
      for (int r = 0; r < 16; ++r) {
        int kl = (r & 3) + 8 * (r >> 2) + 4 * hi;
        if (kl > lim) s1v[r] = -INFINITY;
      }
    }
    {
      uint32_t c0[8], c1[8];
#pragma unroll
      for (int w = 0; w < 8; ++w) {
        float a0 = exp2_fast(s0v[2 * w]), a1 = exp2_fast(s0v[2 * w + 1]);
        c0[w] = pkrtz(a0, a1);
        l0p += a0 + a1;
        float b0 = exp2_fast(s1v[2 * w]), b1 = exp2_fast(s1v[2 * w + 1]);
        c1[w] = pkrtz(b0, b1);
        l1p += b0 + b1;
      }
#pragma unroll
      for (int kk2 = 0; kk2 < 2; ++kk2) {
        uint32_t a0 = c0[4 * kk2 + 0], a2 = c0[4 * kk2 + 2];
        uint32_t a1 = c0[4 * kk2 + 1], a3 = c0[4 * kk2 + 3];
        asm volatile("v_permlane32_swap_b32 %0, %1" : "+v"(a0), "+v"(a2));
        asm volatile("v_permlane32_swap_b32 %0, %1" : "+v"(a1), "+v"(a3));
        pwB0[kk2][0] = a0; pwB0[kk2][1] = a1; pwB0[kk2][2] = a2; pwB0[kk2][3] = a3;
        uint32_t b0 = c1[4 * kk2 + 0], b2 = c1[4 * kk2 + 2];
        uint32_t b1 = c1[4 * kk2 + 1], b3 = c1[4 * kk2 + 3];
        asm volatile("v_permlane32_swap_b32 %0, %1" : "+v"(b0), "+v"(b2));
        asm volatile("v_permlane32_swap_b32 %0, %1" : "+v"(b1), "+v"(b3));
        pwB1[kk2][0] = b0; pwB1[kk2][1] = b1; pwB1[kk2][2] = b2; pwB1[kk2][3] = b3;
      }
    }
    // PV(m1): kk = 2,3
#pragma unroll
    for (int kk2 = 0; kk2 < 2; ++kk2) {
      const int kk = 2 + kk2;
      uint4 fwa; fwa.x = pwB0[kk2][0]; fwa.y = pwB0[kk2][1];
      fwa.z = pwB0[kk2][2]; fwa.w = pwB0[kk2][3];
      f16x8 pa0 = __builtin_bit_cast(f16x8, fwa);
      uint4 fwb; fwb.x = pwB1[kk2][0]; fwb.y = pwB1[kk2][1];
      fwb.z = pwB1[kk2][2]; fwb.w = pwB1[kk2][3];
      f16x8 pa1 = __builtin_bit_cast(f16x8, fwb);
      f16x8 vf0 = frag64h(Vtt, lo5,      (2 * kk + hi) ^ swz5);
      f16x8 vf1 = frag64h(Vtt, 32 + lo5, (2 * kk + hi) ^ swz5);
      o00 = __builtin_amdgcn_mfma_f32_32x32x16_f16(pa0, vf0, o00, 0, 0, 0);
      o01 = __builtin_amdgcn_mfma_f32_32x32x16_f16(pa0, vf1, o01, 0, 0, 0);
      o10 = __builtin_amdgcn_mfma_f32_32x32x16_f16(pa1, vf0, o10, 0, 0, 0);
      o11 = __builtin_amdgcn_mfma_f32_32x32x16_f16(pa1, vf1, o11, 0, 0, 0);
    }
  }

  // cross-hi combine of l partials: one permlane32_swap + add each
  float l0full, l1full;
  {
    float a0 = l0p, b0 = l0p;
    asm volatile("v_permlane32_swap_b32 %0, %1" : "+v"(a0), "+v"(b0));
    l0full = a0 + b0;                       // all lanes: full l for q=qg*64+lo5 (this kp)
    float a1 = l1p, b1 = l1p;
    asm volatile("v_permlane32_swap_b32 %0, %1" : "+v"(a1), "+v"(b1));
    l1full = a1 + b1;
  }

  // epilogue: combine kp partials via LDS, normalize, stage bf16, write out
  const int b = bh >> 4, h = bh & 15;
  float* F = (float*)&Ks[0][0][0];          // 32 KB: [128 q][64 dh] f32
  float* L = (float*)&Vt[1][0][0];          // 1 KB:  [kp][128 q] f32
  uint16_t* Es = &Vt[0][0][0];              // 16 KB: [128 q][64 dh] bf16

  __syncthreads();
  if (hi == 0) {
    L[kp * 128 + qg * 64 + lo5]      = l0full;
    L[kp * 128 + qg * 64 + 32 + lo5] = l1full;
  }
  if (kp == 1) {
#pragma unroll
    for (int r = 0; r < 16; ++r) {
      int q0 = qg * 64 + (r & 3) + 8 * (r >> 2) + 4 * hi;
      int q1 = q0 + 32;
      F[q0 * 64 + lo5]      = o00[r];
      F[q0 * 64 + 32 + lo5] = o01[r];
      F[q1 * 64 + lo5]      = o10[r];
      F[q1 * 64 + 32 + lo5] = o11[r];
    }
  }
  __syncthreads();
  if (kp == 0) {
#pragma unroll
    for (int r = 0; r < 16; ++r) {
      int q0 = qg * 64 + (r & 3) + 8 * (r >> 2) + 4 * hi;
      int q1 = q0 + 32;
      float inv0 = 1.0f / (L[q0] + L[128 + q0]);   // broadcast reads
      float inv1 = 1.0f / (L[q1] + L[128 + q1]);
      Es[q0 * 64 + lo5]      = f2bf((o00[r] + F[q0 * 64 + lo5]) * inv0);
      Es[q0 * 64 + 32 + lo5] = f2bf((o01[r] + F[q0 * 64 + 32 + lo5]) * inv0);
      Es[q1 * 64 + lo5]      = f2bf((o10[r] + F[q1 * 64 + lo5]) * inv1);
      Es[q1 * 64 + 32 + lo5] = f2bf((o11[r] + F[q1 * 64 + 32 + lo5]) * inv1);
    }
  }
  __syncthreads();
  {
    int row = tid >> 1, c32 = (tid & 1) * 32;   // 256 threads -> 128 rows
    size_t base = ((size_t)(b * 2048) + i0 + row) * 1024 + h * 64 + c32;
    *(uint4*)&AO[base]      = *(const uint4*)&Es[row * 64 + c32];
    *(uint4*)&AO[base + 8]  = *(const uint4*)&Es[row * 64 + c32 + 8];
    *(uint4*)&AO[base + 16] = *(const uint4*)&Es[row * 64 + c32 + 16];
    *(uint4*)&AO[base + 24] = *(const uint4*)&Es[row * 64 + c32 + 24];
  }
}

// ---------------------------------------------------------------------------
extern "C" void kernel_launch(void* const* d_in, const int* in_sizes, int n_in,
                              void* d_out, int out_size, void* d_ws,
                              size_t ws_size, hipStream_t stream) {
  const float* x     = (const float*)d_in[0];
  const float* mem_k = (const float*)d_in[1];
  const float* mem_v = (const float*)d_in[2];
  const float* Wq    = (const float*)d_in[3];
  const float* Wkv   = (const float*)d_in[4];
  const float* b_kv  = (const float*)d_in[5];
  const float* Wo    = (const float*)d_in[6];
  const float* b_o   = (const float*)d_in[7];
  float* out = (float*)d_out;

  char* ws = (char*)d_ws;
  uint16_t* Xb    = (uint16_t*)(ws);                         // 8 MB  [4096][1024]
  uint16_t* WallT = (uint16_t*)(ws + (8ull << 20));          // 6 MB  [3072][1024]
  uint16_t* WoT   = (uint16_t*)(ws + (14ull << 20));         // 2 MB  [1024][1024]
  uint16_t* Qh    = (uint16_t*)(ws + (16ull << 20));         // 8 MB  [bh][2048][64]
  uint16_t* Kh    = (uint16_t*)(ws + (24ull << 20));         // 16 MB [bh][4096][64] bf16
  uint16_t* VhT   = (uint16_t*)(ws + (40ull << 20));         // 16 MB [bh][64][4096] fp16
  uint16_t* AO    = (uint16_t*)(ws + (56ull << 20));         // 8 MB  [4096][1024]

  prep_kernel<<<4096, 256, 0, stream>>>(x, mem_k, mem_v, Wq, Wkv, Wo,
                                        Xb, WallT, WoT, Kh, VhT);
  gemm_kernel<0><<<dim3(32, 24), 256, 0, stream>>>(Xb, WallT, b_kv,
                                                   Qh, Kh, VhT, nullptr);
  attn_kernel<<<dim3(32, 16), 256, 0, stream>>>(Qh, Kh, VhT, AO);
  gemm_kernel<1><<<dim3(64, 8), 256, 0, stream>>>(AO, WoT, b_o,
                                                  nullptr, nullptr, nullptr, out);
}